// Round 14
// baseline (138.959 us; speedup 1.0000x reference)
//
#include <hip/hip_runtime.h>
#include <math.h>

#define IMG_H 512
#define IMG_W 512
#define NBATCH 8
#define TILE 32
#define GDIM 36            // TILE + 4 halo
#define NCH 9              // g channels: silu + 8 bases
#define NCONV 16
#define NPOS (GDIM * GDIM)

// ws layout (floats): [0,100) = WCH (25 taps x 8 f16 bases-weights, as h8),
// [128,153) = WCS (25 f32 silu-weights), [256,985) = WV (9 uv x 9 tap x 9 ch)
#define WOFF_WCH 0
#define WOFF_WCS 128
#define WOFF_WV  256

typedef _Float16 h2 __attribute__((ext_vector_type(2)));
typedef _Float16 h8 __attribute__((ext_vector_type(8)));

// ---- g(x) = [silu(x), B0..B7(x)] : closed-form cubic B-spline bases on uniform
// grid t_j=(j-3)*0.4-1. u = x*2.5+5.5 maps knots to integers; i=floor(u), t=u-i.
__device__ __forceinline__ void eval_gb(float x, float& sl, float bj[8]) {
    float u = fmaf(x, 2.5f, 5.5f);
    float fi = floorf(u);
    int i = (int)fi;
    float t = u - fi;
    float s1 = 1.f - t;
    float t2 = t * t, t3 = t2 * t;
    float w0 = s1 * s1 * s1 * (1.f / 6.f);
    float w3 = t3 * (1.f / 6.f);
    float w1v = fmaf(0.5f, t3, 2.f / 3.f) - t2;          // (3t^3-6t^2+4)/6
    float msk = (u >= 0.f && u < 11.f) ? 1.f : 0.f;      // outside grid -> all bases 0
    w0 *= msk; w1v *= msk; w3 *= msk;
    float w2v = msk - w0 - w1v - w3;                     // partition of unity
    sl = x / (1.f + __expf(-x));                         // silu
#pragma unroll
    for (int j = 0; j < 8; ++j) {
        float v = 0.f;
        v = (i == j)     ? w3  : v;
        v = (i == j + 1) ? w2v : v;
        v = (i == j + 2) ? w1v : v;
        v = (i == j + 3) ? w0  : v;
        bj[j] = v;
    }
}

// ---- prep: composed 5x5 kernel (f16 bases + f32 silu) and border-fold weights
// WV[uv][tap][ch] = sum_c rw[c,uv] * W1[c,tap,ch]
__global__ void ConvKAN_prep(const float* __restrict__ bw, const float* __restrict__ sw,
                             const float* __restrict__ ss, const float* __restrict__ rw,
                             float* __restrict__ ws) {
    __shared__ float W1s[NCONV * 81];
    __shared__ float WC[225];
    int t = threadIdx.x;
    for (int idx = t; idx < NCONV * 81; idx += 256) {
        int ci = idx / NCH;
        int ch = idx % NCH;
        W1s[idx] = (ch == 0) ? bw[ci] : sw[ci * 8 + (ch - 1)] * ss[ci];
    }
    __syncthreads();
    // Wc[(d*5+e)*9 + ch] = sum_c sum_{u,v} rw[c,u,v] * W1[c,ch,d-u,e-v]
    if (t < 225) {
        int de = t / NCH, ch = t % NCH;
        int d = de / 5, e = de % 5;
        float s = 0.0f;
        for (int c = 0; c < NCONV; ++c) {
            int ulo = d - 2 > 0 ? d - 2 : 0, uhi = d < 2 ? d : 2;
            int vlo = e - 2 > 0 ? e - 2 : 0, vhi = e < 2 ? e : 2;
            for (int u = ulo; u <= uhi; ++u)
                for (int v = vlo; v <= vhi; ++v) {
                    int i = (d - u) * 3 + (e - v);
                    s += rw[c * 9 + u * 3 + v] * W1s[(c * 9 + i) * NCH + ch];
                }
        }
        WC[t] = s;
    }
    // WV for border correction
    for (int idx = t; idx < 729; idx += 256) {
        int uv = idx / 81, rest = idx % 81;
        float s = 0.f;
        for (int c = 0; c < NCONV; ++c)
            s += rw[c * 9 + uv] * W1s[c * 81 + rest];
        ws[WOFF_WV + idx] = s;
    }
    __syncthreads();
    if (t < 25) {
        h8 hw;
#pragma unroll
        for (int j = 0; j < 8; ++j) hw[j] = (_Float16)WC[t * 9 + 1 + j];
        ((h8*)(ws + WOFF_WCH))[t] = hw;
        ws[WOFF_WCS + t] = WC[t * 9];
    }
}

// ---- main: r13 hot loop byte-identical; border correction fused into the
// epilogue of edge blocks (correction g-values are already in the LDS halo).
__global__ __launch_bounds__(256) void ConvKAN_main(const float* __restrict__ x,
                                                    const float* __restrict__ wpack,
                                                    const float* __restrict__ wsl,
                                                    const float* __restrict__ wv,
                                                    const float* __restrict__ rb,
                                                    float* __restrict__ out) {
    __shared__ h8 HB[NPOS];       // bases 0..7 as f16x8 (16B)
    __shared__ float SS[NPOS];    // silu (f32)
    __shared__ float WVs[729];    // border-fold weights (edge blocks only)
    int tid = threadIdx.x;
    int b = blockIdx.z;
    int y0 = blockIdx.y * TILE, x0 = blockIdx.x * TILE;
    const float* xb = x + (size_t)b * IMG_H * IMG_W;

    bool edge = (y0 == 0) || (y0 + TILE == IMG_H) || (x0 == 0) || (x0 + TILE == IMG_W);
    if (edge)
        for (int idx = tid; idx < 729; idx += 256) WVs[idx] = wv[idx];

    for (int i = tid; i < NPOS; i += 256) {
        int r = i / GDIM, c = i % GDIM;
        int gy = y0 + r - 2, gx = x0 + c - 2;
        float xv = (gy >= 0 && gy < IMG_H && gx >= 0 && gx < IMG_W) ? xb[gy * IMG_W + gx] : 0.0f;
        float sl, bj[8];
        eval_gb(xv, sl, bj);   // OOB -> g(0): matches zero-padded im2col semantics
        h8 hv;
#pragma unroll
        for (int j = 0; j < 8; ++j) hv[j] = (_Float16)bj[j];
        HB[i] = hv; SS[i] = sl;
    }
    __syncthreads();

    int tx = tid & 31;
    int ty = tid >> 5;          // 0..7
    int r0 = ty * 4;            // first output row (tile coords) of this thread
    float bias = rb[0];
    float acc[4] = {bias, bias, bias, bias};

#pragma unroll
    for (int R = 0; R < 8; ++R) {       // g rows r0+R cover rows needed by pixels p=0..3
#pragma unroll
        for (int e = 0; e < 5; ++e) {
            int pos = (r0 + R) * GDIM + tx + e;
            h8 hv = HB[pos]; float sl = SS[pos];
            h2 b0 = {hv[0], hv[1]}, b1 = {hv[2], hv[3]};
            h2 b2 = {hv[4], hv[5]}, b3 = {hv[6], hv[7]};
#pragma unroll
            for (int p = 0; p < 4; ++p) {
                int d = R - p;
                if (d < 0 || d > 4) continue;          // compile-time eliminated
                int t = d * 5 + e;
                const h2* wh = (const h2*)&wpack[t * 4];   // 8 f16 = 4 floats per tap
                float a0 = fmaf(sl, wsl[t], acc[p]);
                a0 = __builtin_amdgcn_fdot2(b0, wh[0], a0, false);
                a0 = __builtin_amdgcn_fdot2(b1, wh[1], a0, false);
                a0 = __builtin_amdgcn_fdot2(b2, wh[2], a0, false);
                a0 = __builtin_amdgcn_fdot2(b3, wh[3], a0, false);
                acc[p] = a0;
            }
        }
    }

    // ---- fused border correction: subtract virtual-feat contributions.
    // Only threads owning image-border pixels do work; g comes from the LDS halo.
    if (edge) {
        int xg = x0 + tx;
#pragma unroll
        for (int p = 0; p < 4; ++p) {
            int yg = y0 + r0 + p;
            if (yg == 0 || yg == IMG_H - 1 || xg == 0 || xg == IMG_W - 1) {
                float corr = 0.f;
#pragma unroll 1
                for (int uv = 0; uv < 9; ++uv) {
                    int du = uv / 3 - 1, dv = uv % 3 - 1;
                    int fy = yg + du, fx = xg + dv;
                    if (fy >= 0 && fy < IMG_H && fx >= 0 && fx < IMG_W) continue; // inside feat
                    const float* wvp = &WVs[uv * 81];
#pragma unroll
                    for (int tap = 0; tap < 9; ++tap) {
                        int gy = fy + tap / 3 - 1, gx = fx + tap % 3 - 1;
                        int pos = (gy - y0 + 2) * GDIM + (gx - x0 + 2);  // in halo by construction
                        h8 hv = HB[pos]; float sl = SS[pos];
                        const float* wq = &wvp[tap * 9];
                        float s = sl * wq[0];
                        s = fmaf((float)hv[0], wq[1], s); s = fmaf((float)hv[1], wq[2], s);
                        s = fmaf((float)hv[2], wq[3], s); s = fmaf((float)hv[3], wq[4], s);
                        s = fmaf((float)hv[4], wq[5], s); s = fmaf((float)hv[5], wq[6], s);
                        s = fmaf((float)hv[6], wq[7], s); s = fmaf((float)hv[7], wq[8], s);
                        corr += s;
                    }
                }
                acc[p] -= corr;
            }
        }
    }

    float* ob = out + ((size_t)b * IMG_H + y0) * IMG_W + x0;
#pragma unroll
    for (int p = 0; p < 4; ++p)
        ob[(r0 + p) * IMG_W + tx] = acc[p];
}

extern "C" void kernel_launch(void* const* d_in, const int* in_sizes, int n_in,
                              void* d_out, int out_size, void* d_ws, size_t ws_size,
                              hipStream_t stream) {
    const float* x  = (const float*)d_in[0];
    const float* bw = (const float*)d_in[1];
    const float* sw = (const float*)d_in[2];
    const float* ss = (const float*)d_in[3];
    const float* rw = (const float*)d_in[4];
    const float* rb = (const float*)d_in[5];
    float* out = (float*)d_out;
    float* ws  = (float*)d_ws;

    ConvKAN_prep<<<1, 256, 0, stream>>>(bw, sw, ss, rw, ws);
    ConvKAN_main<<<dim3(IMG_W / TILE, IMG_H / TILE, NBATCH), 256, 0, stream>>>(
        x, ws + WOFF_WCH, ws + WOFF_WCS, ws + WOFF_WV, rb, out);
}